// Round 12
// baseline (1183.774 us; speedup 1.0000x reference)
//
#include <hip/hip_runtime.h>
#include <hip/hip_bf16.h>

#define N_NODES 8192
#define N_EDGES 262144
#define F_INDIM 128
#define HID 256
#define F_OUT 128
#define N_GRAPHS 64
#define WPR 256              // words per bitmask row
#define CAP 160              // max supported degree
#define NB 1024              // megakernel grid (4 blocks/CU x 256 CU)

struct alignas(8) bf4 { __hip_bfloat16 a, b, c, d; };

__device__ inline float2 bf2unpack(unsigned int u) {
    float2 r;
    r.x = __uint_as_float(u << 16);
    r.y = __uint_as_float(u & 0xffff0000u);
    return r;
}

// Phase-overlaid LDS (max 12.3 KB -> 4 blocks/CU uses 49 KB of 160 KB)
union alignas(16) SMem {
    struct { int nb[4][CAP]; float nbd[4][CAP]; float ul[4][64]; } p1;  // 6.1 KB
    struct { float xs[8][F_INDIM]; float hs[8][HID]; } p2;              // 12.3 KB
    struct { float us[2][256]; } p3;                                    // 2 KB
};

// ---------------------------------------------------------------------------
// Device-scope grid barrier. Requires all NB blocks co-resident (enforced by
// __launch_bounds__(256,4): 4 blocks/CU x 256 CUs = 1024 = NB). Spin is
// guarded: on pathological failure it breaks (wrong answer, not a hang).
// ---------------------------------------------------------------------------
__device__ inline void gridbar(int* bar) {
    __threadfence();                      // release my global writes (device)
    __syncthreads();
    if (threadIdx.x == 0) {
        int g = atomicAdd(&bar[1], 0);    // atomic read of generation
        if (atomicAdd(&bar[0], 1) == NB - 1) {
            atomicExch(&bar[0], 0);       // reset BEFORE bumping generation
            atomicAdd(&bar[1], 1);
        } else {
            int guard = 0;
            while (atomicAdd(&bar[1], 0) == g && ++guard < (1 << 28)) {}
        }
    }
    __syncthreads();
    __threadfence();                      // acquire: invalidate stale caches
}

// ---------------------------------------------------------------------------
// init: zero barrier state + zero out (both poisoned 0xAA before every call)
// ---------------------------------------------------------------------------
__global__ __launch_bounds__(256) void init_bar(int* bar, float* out) {
    if (threadIdx.x < 2) bar[threadIdx.x] = 0;
    float4 z = {0, 0, 0, 0};
    for (int v = threadIdx.x; v < N_GRAPHS * F_OUT / 4; v += 256)
        ((float4*)out)[v] = z;
}

// ---------------------------------------------------------------------------
// megakernel: Pa cast+maskzero | Pb scatter | P0 dis | P1 spmm+sv+u |
//             P2 fused 2-layer gemm | P3 weighted pool
// ---------------------------------------------------------------------------
__global__ __launch_bounds__(256, 4) void mega(
    const float* __restrict__ X, const float* __restrict__ W1,
    const float* __restrict__ b1, const float* __restrict__ W2,
    const float* __restrict__ b2, const int* __restrict__ ei,
    const int* __restrict__ batch, __hip_bfloat16* __restrict__ Xh,
    unsigned int* __restrict__ mask, float* __restrict__ dis,
    float* __restrict__ sv, float* __restrict__ G,
    __hip_bfloat16* __restrict__ M2ph, float* __restrict__ u,
    float* __restrict__ out, int* bar)
{
    __shared__ SMem sm;
    int t = threadIdx.x;
    int tid = blockIdx.x * 256 + t;        // 0..262143
    int lane = t & 63;
    int w = t >> 6;
    int gwid = tid >> 6;                   // global wave id 0..4095

    // ---- Pa: cast X->bf16 (1 float4/thread) + zero mask (2 uint4/thread) --
    {
        float4 v = ((const float4*)X)[tid];
        bf4 o;
        o.a = __float2bfloat16(v.x); o.b = __float2bfloat16(v.y);
        o.c = __float2bfloat16(v.z); o.d = __float2bfloat16(v.w);
        ((bf4*)Xh)[tid] = o;
        uint4 z = {0u, 0u, 0u, 0u};
        ((uint4*)mask)[tid] = z;
        ((uint4*)mask)[tid + 262144] = z;
    }
    gridbar(bar);
    // ---- Pb: scatter, 2 edges/thread (threads 0..131071) [R2-proven] ------
    if (tid < N_EDGES / 2) {
        int2 s2 = ((const int2*)ei)[tid];
        int2 d2 = ((const int2*)(ei + N_EDGES))[tid];
        if ((unsigned)s2.x < N_NODES && (unsigned)d2.x < N_NODES) {
            atomicOr(&mask[(size_t)s2.x * WPR + (d2.x >> 5)], 1u << (d2.x & 31));
            atomicOr(&mask[(size_t)d2.x * WPR + (s2.x >> 5)], 1u << (s2.x & 31));
        }
        if ((unsigned)s2.y < N_NODES && (unsigned)d2.y < N_NODES) {
            atomicOr(&mask[(size_t)s2.y * WPR + (d2.y >> 5)], 1u << (d2.y & 31));
            atomicOr(&mask[(size_t)d2.y * WPR + (s2.y >> 5)], 1u << (s2.y & 31));
        }
    }
    gridbar(bar);
    // ---- P0: dis = rsqrt(deg+1); wave handles rows 2*gwid, 2*gwid+1 ------
    for (int rep = 0; rep < 2; ++rep) {
        int row = gwid * 2 + rep;
        uint4 v = ((const uint4*)(mask + (size_t)row * WPR))[lane];
        int c = __popc(v.x) + __popc(v.y) + __popc(v.z) + __popc(v.w);
        for (int off = 32; off; off >>= 1) c += __shfl_down(c, off);
        if (lane == 0) dis[row] = rsqrtf((float)(c + 1));
    }
    gridbar(bar);
    // ---- P1: spmm + sv + u; wave per row, 2 rows/wave [R10-proven body] ---
    for (int rep = 0; rep < 2; ++rep) {
        int i = gwid * 2 + rep;
        sm.p1.ul[w][lane] = 0.0f;
        uint4 v = ((const uint4*)(mask + (size_t)i * WPR))[lane];
        int cnt = __popc(v.x) + __popc(v.y) + __popc(v.z) + __popc(v.w);
        int scan = cnt;
        for (int off = 1; off < 64; off <<= 1) {
            int n = __shfl_up(scan, off);
            if (lane >= off) scan += n;
        }
        int tot = __shfl(scan, 63);
        int idx = scan - cnt;
        int wbase = lane << 7;
        unsigned int wd;
        wd = v.x; while (wd) { int b = __ffs(wd) - 1; wd &= wd - 1; if (idx < CAP) sm.p1.nb[w][idx] = wbase + b;      ++idx; }
        wd = v.y; while (wd) { int b = __ffs(wd) - 1; wd &= wd - 1; if (idx < CAP) sm.p1.nb[w][idx] = wbase + 32 + b; ++idx; }
        wd = v.z; while (wd) { int b = __ffs(wd) - 1; wd &= wd - 1; if (idx < CAP) sm.p1.nb[w][idx] = wbase + 64 + b; ++idx; }
        wd = v.w; while (wd) { int b = __ffs(wd) - 1; wd &= wd - 1; if (idx < CAP) sm.p1.nb[w][idx] = wbase + 96 + b; ++idx; }
        int d = tot > CAP ? CAP : tot;
        float p = 0.0f;
        for (int k2 = lane; k2 < d; k2 += 64) {
            int j = sm.p1.nb[w][k2];
            float dj = dis[j];
            sm.p1.nbd[w][k2] = dj;
            p += dj;
            atomicAdd(&sm.p1.ul[w][batch[j] & 63], dj);
        }
        for (int off = 32; off; off >>= 1) p += __shfl_down(p, off);
        float di = dis[i];
        if (lane == 0) {
            sv[i] = di * (di + __shfl(p, 0));
            atomicAdd(&sm.p1.ul[w][batch[i] & 63], di);   // +I diagonal
        }
        const unsigned int* Xu = (const unsigned int*)Xh;
        float2 xi = bf2unpack(Xu[(size_t)i * 64 + lane]);
        float2 a0 = {di * xi.x, di * xi.y};
        float2 a1 = {0,0}, a2 = {0,0}, a3 = {0,0}, a4 = {0,0}, a5 = {0,0}, a6 = {0,0}, a7 = {0,0};
        int k = 0;
        for (; k + 8 <= d; k += 8) {
#define GATH(Q, ACC) { int j = sm.p1.nb[w][k+Q]; float dj = sm.p1.nbd[w][k+Q]; \
            float2 f = bf2unpack(Xu[(size_t)j * 64 + lane]); \
            ACC.x += dj * f.x; ACC.y += dj * f.y; }
            GATH(0, a0) GATH(1, a1) GATH(2, a2) GATH(3, a3)
            GATH(4, a4) GATH(5, a5) GATH(6, a6) GATH(7, a7)
        }
        for (; k < d; ++k) GATH(0, a0)
#undef GATH
        float2 s;
        s.x = ((a0.x + a1.x) + (a2.x + a3.x)) + ((a4.x + a5.x) + (a6.x + a7.x));
        s.y = ((a0.y + a1.y) + (a2.y + a3.y)) + ((a4.y + a5.y) + (a6.y + a7.y));
        float2 o = {di * s.x, di * s.y};
        ((float2*)(G + (size_t)i * F_INDIM))[lane] = o;
        u[(size_t)i * N_GRAPHS + lane] = sm.p1.ul[w][lane];
    }
    gridbar(bar);
    // ---- P2: fused 2-layer gemm, 8-row tile per block [R8-proven math] ----
    {
        int i0 = blockIdx.x * 8;
        *(float4*)&sm.p2.xs[t >> 5][(t & 31) << 2] =
            *(const float4*)&G[(size_t)(i0 + (t >> 5)) * F_INDIM + ((t & 31) << 2)];
        __syncthreads();
        {   // stage 1: 2 rows x 4 cols/thread over K=128
            int tc = t & 63, tr = t >> 6;
            float4 acc0 = {0,0,0,0}, acc1 = {0,0,0,0};
            const float* wp = W1 + 4 * tc;
            for (int k = 0; k < F_INDIM; k += 4) {
                float4 w0 = *(const float4*)&wp[(size_t)(k + 0) * HID];
                float4 w1 = *(const float4*)&wp[(size_t)(k + 1) * HID];
                float4 w2 = *(const float4*)&wp[(size_t)(k + 2) * HID];
                float4 w3 = *(const float4*)&wp[(size_t)(k + 3) * HID];
#define ROW(R, ACC) { \
                float4 g4 = *(const float4*)&sm.p2.xs[2 * tr + R][k]; \
                ACC.x += g4.x*w0.x; ACC.y += g4.x*w0.y; ACC.z += g4.x*w0.z; ACC.w += g4.x*w0.w; \
                ACC.x += g4.y*w1.x; ACC.y += g4.y*w1.y; ACC.z += g4.y*w1.z; ACC.w += g4.y*w1.w; \
                ACC.x += g4.z*w2.x; ACC.y += g4.z*w2.y; ACC.z += g4.z*w2.z; ACC.w += g4.z*w2.w; \
                ACC.x += g4.w*w3.x; ACC.y += g4.w*w3.y; ACC.z += g4.w*w3.z; ACC.w += g4.w*w3.w; }
                ROW(0, acc0) ROW(1, acc1)
#undef ROW
            }
            float4 b = *(const float4*)&b1[4 * tc];
#define EPI(R, ACC) { \
            int r = 2 * tr + R; float s = sv[i0 + r]; float4 res = ACC; \
            sm.p2.hs[r][4 * tc + 0] = fmaxf(res.x + s * b.x, 0.f); \
            sm.p2.hs[r][4 * tc + 1] = fmaxf(res.y + s * b.y, 0.f); \
            sm.p2.hs[r][4 * tc + 2] = fmaxf(res.z + s * b.z, 0.f); \
            sm.p2.hs[r][4 * tc + 3] = fmaxf(res.w + s * b.w, 0.f); }
            EPI(0, acc0) EPI(1, acc1)
#undef EPI
        }
        __syncthreads();
        {   // stage 2: 1 row x 4 cols/thread over K=256
            int tc = t & 31, r = t >> 5;
            float4 acc = {0,0,0,0};
            const float* wp = W2 + 4 * tc;
            for (int k = 0; k < HID; k += 4) {
                float4 w0 = *(const float4*)&wp[(size_t)(k + 0) * F_OUT];
                float4 w1 = *(const float4*)&wp[(size_t)(k + 1) * F_OUT];
                float4 w2 = *(const float4*)&wp[(size_t)(k + 2) * F_OUT];
                float4 w3 = *(const float4*)&wp[(size_t)(k + 3) * F_OUT];
                float4 g4 = *(const float4*)&sm.p2.hs[r][k];
                acc.x += g4.x*w0.x; acc.y += g4.x*w0.y; acc.z += g4.x*w0.z; acc.w += g4.x*w0.w;
                acc.x += g4.y*w1.x; acc.y += g4.y*w1.y; acc.z += g4.y*w1.z; acc.w += g4.y*w1.w;
                acc.x += g4.z*w2.x; acc.y += g4.z*w2.y; acc.z += g4.z*w2.z; acc.w += g4.z*w2.w;
                acc.x += g4.w*w3.x; acc.y += g4.w*w3.y; acc.z += g4.w*w3.z; acc.w += g4.w*w3.w;
            }
            float4 b = *(const float4*)&b2[4 * tc];
            int i = i0 + r;
            float dd = dis[i];
            bf4 o;
            o.a = __float2bfloat16(dd * (acc.x + b.x));
            o.b = __float2bfloat16(dd * (acc.y + b.y));
            o.c = __float2bfloat16(dd * (acc.z + b.z));
            o.d = __float2bfloat16(dd * (acc.w + b.w));
            *(bf4*)(M2ph + (size_t)i * F_OUT + 4 * tc) = o;
        }
    }
    gridbar(bar);
    // ---- P3: weighted pool; block = (g, 512-row chunk), 2 subs x 256 rows -
    {
        int g = blockIdx.x >> 4, q = blockIdx.x & 15;
        int c = t & 127, sub = t >> 7;
        int j0 = q * 512 + sub * 256;
        const unsigned short* Mu = (const unsigned short*)M2ph;
        sm.p3.us[sub][c]       = u[(size_t)(j0 + c) * N_GRAPHS + g];
        sm.p3.us[sub][c + 128] = u[(size_t)(j0 + c + 128) * N_GRAPHS + g];
        __syncthreads();
        float a0 = 0.f, a1 = 0.f, a2 = 0.f, a3 = 0.f, a4 = 0.f, a5 = 0.f, a6 = 0.f, a7 = 0.f;
        for (int jj = 0; jj < 256; jj += 8) {
#define TERM(Q, ACC) ACC += sm.p3.us[sub][jj + Q] * \
            __uint_as_float((unsigned)Mu[(size_t)(j0 + jj + Q) * F_OUT + c] << 16);
            TERM(0, a0) TERM(1, a1) TERM(2, a2) TERM(3, a3)
            TERM(4, a4) TERM(5, a5) TERM(6, a6) TERM(7, a7)
#undef TERM
        }
        float s = ((a0 + a1) + (a2 + a3)) + ((a4 + a5) + (a6 + a7));
        int lo = 0, hi = N_NODES;
        while (lo < hi) { int m = (lo + hi) >> 1; if (batch[m] < g) lo = m + 1; else hi = m; }
        int start = lo;
        hi = N_NODES;
        while (lo < hi) { int m = (lo + hi) >> 1; if (batch[m] < g + 1) lo = m + 1; else hi = m; }
        int cnt = lo - start;
        atomicAdd(&out[(size_t)g * F_OUT + c], s / (float)(cnt > 0 ? cnt : 1));
    }
}

// ---------------------------------------------------------------------------
extern "C" void kernel_launch(void* const* d_in, const int* in_sizes, int n_in,
                              void* d_out, int out_size, void* d_ws, size_t ws_size,
                              hipStream_t stream) {
    const float* X  = (const float*)d_in[0];
    const float* W1 = (const float*)d_in[1];
    const float* b1 = (const float*)d_in[2];
    const float* W2 = (const float*)d_in[3];
    const float* b2 = (const float*)d_in[4];
    const int* ei    = (const int*)d_in[5];
    const int* batch = (const int*)d_in[6];
    float* out = (float*)d_out;

    char* ws = (char*)d_ws;
    // [0,8MB): mask; [2MB,4MB) reused for M2ph (written in P2, after P1's
    // last mask read, barrier-ordered). u/G/Xh do not alias mask.
    unsigned int* mask   = (unsigned int*)(ws);
    __hip_bfloat16* M2ph = (__hip_bfloat16*)(ws + 2097152); // 2 MB
    float* G   = (float*)(ws + 8388608);                    // 4 MB
    __hip_bfloat16* Xh = (__hip_bfloat16*)(ws + 12582912);  // 2 MB
    float* u   = (float*)(ws + 14680064);                   // 2 MB (8192x64)
    float* dis = (float*)(ws + 30441472);                   // 32 KB
    float* sv  = (float*)(ws + 30474240);                   // 32 KB
    int*   bar = (int*)(ws + 33554432);                     // 8 B barrier state

    init_bar<<<1, 256, 0, stream>>>(bar, out);
    mega<<<NB, 256, 0, stream>>>(X, W1, b1, W2, b2, ei, batch,
                                 Xh, mask, dis, sv, G, M2ph, u, out, bar);
}

// Round 14
// 1135.259 us; speedup vs baseline: 1.0427x; 1.0427x over previous
//
#include <hip/hip_runtime.h>
#include <hip/hip_bf16.h>

#define N_NODES 8192
#define N_EDGES 262144
#define F_INDIM 128
#define HID 256
#define F_OUT 128
#define N_GRAPHS 64
#define WPR 256              // words per bitmask row
#define CAP 160              // max supported degree
#define NB 1024              // megakernel grid (4 blocks/CU x 256 CU)

struct alignas(8) bf4 { __hip_bfloat16 a, b, c, d; };

__device__ inline float2 bf2unpack(unsigned int u) {
    float2 r;
    r.x = __uint_as_float(u << 16);
    r.y = __uint_as_float(u & 0xffff0000u);
    return r;
}

// Phase-overlaid LDS (max 12.3 KB -> 4 blocks/CU uses 49 KB of 160 KB)
union alignas(16) SMem {
    struct { int nb[4][CAP]; float nbd[4][CAP]; float ul[4][64]; } p1;  // 6.1 KB
    struct { float xs[8][F_INDIM]; float hs[8][HID]; } p2;              // 12.3 KB
    struct { float us[2][256]; } p3;                                    // 2 KB
};

// ---------------------------------------------------------------------------
// Device-scope grid barrier, contention-minimized:
//  - arrival: ONE fetch_add per block (1024 serialized RMWs ~ 2-3 us)
//  - spin: plain agent-scope atomic LOAD (no RMW) + s_sleep backoff
// All NB blocks co-resident (__launch_bounds__(256,4) -> 4/CU x 256 CU).
// Guarded spin: pathological failure breaks (wrong answer, not hang).
// ---------------------------------------------------------------------------
__device__ inline void gridbar(int* bar) {
    __syncthreads();
    if (threadIdx.x == 0) {
        __threadfence();                  // release my block's plain writes
        int g = __hip_atomic_load(&bar[1], __ATOMIC_ACQUIRE,
                                  __HIP_MEMORY_SCOPE_AGENT);
        int arrived = __hip_atomic_fetch_add(&bar[0], 1, __ATOMIC_ACQ_REL,
                                             __HIP_MEMORY_SCOPE_AGENT);
        if (arrived == NB - 1) {
            __hip_atomic_store(&bar[0], 0, __ATOMIC_RELAXED,
                               __HIP_MEMORY_SCOPE_AGENT);
            __hip_atomic_store(&bar[1], g + 1, __ATOMIC_RELEASE,
                               __HIP_MEMORY_SCOPE_AGENT);
        } else {
            int guard = 0;
            while (__hip_atomic_load(&bar[1], __ATOMIC_ACQUIRE,
                                     __HIP_MEMORY_SCOPE_AGENT) == g &&
                   ++guard < (1 << 27)) {
                __builtin_amdgcn_s_sleep(1);
            }
        }
        __threadfence();                  // acquire side for plain data
    }
    __syncthreads();
}

// ---------------------------------------------------------------------------
// init: zero barrier state + zero out (both poisoned 0xAA before every call)
// ---------------------------------------------------------------------------
__global__ __launch_bounds__(256) void init_bar(int* bar, float* out) {
    if (threadIdx.x < 2) bar[threadIdx.x] = 0;
    float4 z = {0, 0, 0, 0};
    for (int v = threadIdx.x; v < N_GRAPHS * F_OUT / 4; v += 256)
        ((float4*)out)[v] = z;
}

// ---------------------------------------------------------------------------
// megakernel: Pa cast+maskzero | Pb scatter | P0 dis | P1 spmm+sv+u |
//             P2 fused 2-layer gemm | P3 weighted pool   [bodies R12-proven]
// ---------------------------------------------------------------------------
__global__ __launch_bounds__(256, 4) void mega(
    const float* __restrict__ X, const float* __restrict__ W1,
    const float* __restrict__ b1, const float* __restrict__ W2,
    const float* __restrict__ b2, const int* __restrict__ ei,
    const int* __restrict__ batch, __hip_bfloat16* __restrict__ Xh,
    unsigned int* __restrict__ mask, float* __restrict__ dis,
    float* __restrict__ sv, float* __restrict__ G,
    __hip_bfloat16* __restrict__ M2ph, float* __restrict__ u,
    float* __restrict__ out, int* bar)
{
    __shared__ SMem sm;
    int t = threadIdx.x;
    int tid = blockIdx.x * 256 + t;        // 0..262143
    int lane = t & 63;
    int w = t >> 6;
    int gwid = tid >> 6;                   // global wave id 0..4095

    // ---- Pa: cast X->bf16 (1 float4/thread) + zero mask (2 uint4/thread) --
    {
        float4 v = ((const float4*)X)[tid];
        bf4 o;
        o.a = __float2bfloat16(v.x); o.b = __float2bfloat16(v.y);
        o.c = __float2bfloat16(v.z); o.d = __float2bfloat16(v.w);
        ((bf4*)Xh)[tid] = o;
        uint4 z = {0u, 0u, 0u, 0u};
        ((uint4*)mask)[tid] = z;
        ((uint4*)mask)[tid + 262144] = z;
    }
    gridbar(bar);
    // ---- Pb: scatter, 2 edges/thread (threads 0..131071) [R2-proven] ------
    if (tid < N_EDGES / 2) {
        int2 s2 = ((const int2*)ei)[tid];
        int2 d2 = ((const int2*)(ei + N_EDGES))[tid];
        if ((unsigned)s2.x < N_NODES && (unsigned)d2.x < N_NODES) {
            atomicOr(&mask[(size_t)s2.x * WPR + (d2.x >> 5)], 1u << (d2.x & 31));
            atomicOr(&mask[(size_t)d2.x * WPR + (s2.x >> 5)], 1u << (s2.x & 31));
        }
        if ((unsigned)s2.y < N_NODES && (unsigned)d2.y < N_NODES) {
            atomicOr(&mask[(size_t)s2.y * WPR + (d2.y >> 5)], 1u << (d2.y & 31));
            atomicOr(&mask[(size_t)d2.y * WPR + (s2.y >> 5)], 1u << (s2.y & 31));
        }
    }
    gridbar(bar);
    // ---- P0: dis = rsqrt(deg+1); wave handles rows 2*gwid, 2*gwid+1 ------
    for (int rep = 0; rep < 2; ++rep) {
        int row = gwid * 2 + rep;
        uint4 v = ((const uint4*)(mask + (size_t)row * WPR))[lane];
        int c = __popc(v.x) + __popc(v.y) + __popc(v.z) + __popc(v.w);
        for (int off = 32; off; off >>= 1) c += __shfl_down(c, off);
        if (lane == 0) dis[row] = rsqrtf((float)(c + 1));
    }
    gridbar(bar);
    // ---- P1: spmm + sv + u; wave per row, 2 rows/wave [R10-proven body] ---
    for (int rep = 0; rep < 2; ++rep) {
        int i = gwid * 2 + rep;
        sm.p1.ul[w][lane] = 0.0f;
        uint4 v = ((const uint4*)(mask + (size_t)i * WPR))[lane];
        int cnt = __popc(v.x) + __popc(v.y) + __popc(v.z) + __popc(v.w);
        int scan = cnt;
        for (int off = 1; off < 64; off <<= 1) {
            int n = __shfl_up(scan, off);
            if (lane >= off) scan += n;
        }
        int tot = __shfl(scan, 63);
        int idx = scan - cnt;
        int wbase = lane << 7;
        unsigned int wd;
        wd = v.x; while (wd) { int b = __ffs(wd) - 1; wd &= wd - 1; if (idx < CAP) sm.p1.nb[w][idx] = wbase + b;      ++idx; }
        wd = v.y; while (wd) { int b = __ffs(wd) - 1; wd &= wd - 1; if (idx < CAP) sm.p1.nb[w][idx] = wbase + 32 + b; ++idx; }
        wd = v.z; while (wd) { int b = __ffs(wd) - 1; wd &= wd - 1; if (idx < CAP) sm.p1.nb[w][idx] = wbase + 64 + b; ++idx; }
        wd = v.w; while (wd) { int b = __ffs(wd) - 1; wd &= wd - 1; if (idx < CAP) sm.p1.nb[w][idx] = wbase + 96 + b; ++idx; }
        int d = tot > CAP ? CAP : tot;
        float p = 0.0f;
        for (int k2 = lane; k2 < d; k2 += 64) {
            int j = sm.p1.nb[w][k2];
            float dj = dis[j];
            sm.p1.nbd[w][k2] = dj;
            p += dj;
            atomicAdd(&sm.p1.ul[w][batch[j] & 63], dj);
        }
        for (int off = 32; off; off >>= 1) p += __shfl_down(p, off);
        float di = dis[i];
        if (lane == 0) {
            sv[i] = di * (di + p);
            atomicAdd(&sm.p1.ul[w][batch[i] & 63], di);   // +I diagonal
        }
        const unsigned int* Xu = (const unsigned int*)Xh;
        float2 xi = bf2unpack(Xu[(size_t)i * 64 + lane]);
        float2 a0 = {di * xi.x, di * xi.y};
        float2 a1 = {0,0}, a2 = {0,0}, a3 = {0,0}, a4 = {0,0}, a5 = {0,0}, a6 = {0,0}, a7 = {0,0};
        int k = 0;
        for (; k + 8 <= d; k += 8) {
#define GATH(Q, ACC) { int j = sm.p1.nb[w][k+Q]; float dj = sm.p1.nbd[w][k+Q]; \
            float2 f = bf2unpack(Xu[(size_t)j * 64 + lane]); \
            ACC.x += dj * f.x; ACC.y += dj * f.y; }
            GATH(0, a0) GATH(1, a1) GATH(2, a2) GATH(3, a3)
            GATH(4, a4) GATH(5, a5) GATH(6, a6) GATH(7, a7)
        }
        for (; k < d; ++k) GATH(0, a0)
#undef GATH
        float2 s;
        s.x = ((a0.x + a1.x) + (a2.x + a3.x)) + ((a4.x + a5.x) + (a6.x + a7.x));
        s.y = ((a0.y + a1.y) + (a2.y + a3.y)) + ((a4.y + a5.y) + (a6.y + a7.y));
        float2 o = {di * s.x, di * s.y};
        ((float2*)(G + (size_t)i * F_INDIM))[lane] = o;
        u[(size_t)i * N_GRAPHS + lane] = sm.p1.ul[w][lane];
    }
    gridbar(bar);
    // ---- P2: fused 2-layer gemm, 8-row tile per block [R8-proven math] ----
    {
        int i0 = blockIdx.x * 8;
        *(float4*)&sm.p2.xs[t >> 5][(t & 31) << 2] =
            *(const float4*)&G[(size_t)(i0 + (t >> 5)) * F_INDIM + ((t & 31) << 2)];
        __syncthreads();
        {   // stage 1: 2 rows x 4 cols/thread over K=128
            int tc = t & 63, tr = t >> 6;
            float4 acc0 = {0,0,0,0}, acc1 = {0,0,0,0};
            const float* wp = W1 + 4 * tc;
            for (int k = 0; k < F_INDIM; k += 4) {
                float4 w0 = *(const float4*)&wp[(size_t)(k + 0) * HID];
                float4 w1 = *(const float4*)&wp[(size_t)(k + 1) * HID];
                float4 w2 = *(const float4*)&wp[(size_t)(k + 2) * HID];
                float4 w3 = *(const float4*)&wp[(size_t)(k + 3) * HID];
#define ROW(R, ACC) { \
                float4 g4 = *(const float4*)&sm.p2.xs[2 * tr + R][k]; \
                ACC.x += g4.x*w0.x; ACC.y += g4.x*w0.y; ACC.z += g4.x*w0.z; ACC.w += g4.x*w0.w; \
                ACC.x += g4.y*w1.x; ACC.y += g4.y*w1.y; ACC.z += g4.y*w1.z; ACC.w += g4.y*w1.w; \
                ACC.x += g4.z*w2.x; ACC.y += g4.z*w2.y; ACC.z += g4.z*w2.z; ACC.w += g4.z*w2.w; \
                ACC.x += g4.w*w3.x; ACC.y += g4.w*w3.y; ACC.z += g4.w*w3.z; ACC.w += g4.w*w3.w; }
                ROW(0, acc0) ROW(1, acc1)
#undef ROW
            }
            float4 b = *(const float4*)&b1[4 * tc];
#define EPI(R, ACC) { \
            int r = 2 * tr + R; float s = sv[i0 + r]; float4 res = ACC; \
            sm.p2.hs[r][4 * tc + 0] = fmaxf(res.x + s * b.x, 0.f); \
            sm.p2.hs[r][4 * tc + 1] = fmaxf(res.y + s * b.y, 0.f); \
            sm.p2.hs[r][4 * tc + 2] = fmaxf(res.z + s * b.z, 0.f); \
            sm.p2.hs[r][4 * tc + 3] = fmaxf(res.w + s * b.w, 0.f); }
            EPI(0, acc0) EPI(1, acc1)
#undef EPI
        }
        __syncthreads();
        {   // stage 2: 1 row x 4 cols/thread over K=256
            int tc = t & 31, r = t >> 5;
            float4 acc = {0,0,0,0};
            const float* wp = W2 + 4 * tc;
            for (int k = 0; k < HID; k += 4) {
                float4 w0 = *(const float4*)&wp[(size_t)(k + 0) * F_OUT];
                float4 w1 = *(const float4*)&wp[(size_t)(k + 1) * F_OUT];
                float4 w2 = *(const float4*)&wp[(size_t)(k + 2) * F_OUT];
                float4 w3 = *(const float4*)&wp[(size_t)(k + 3) * F_OUT];
                float4 g4 = *(const float4*)&sm.p2.hs[r][k];
                acc.x += g4.x*w0.x; acc.y += g4.x*w0.y; acc.z += g4.x*w0.z; acc.w += g4.x*w0.w;
                acc.x += g4.y*w1.x; acc.y += g4.y*w1.y; acc.z += g4.y*w1.z; acc.w += g4.y*w1.w;
                acc.x += g4.z*w2.x; acc.y += g4.z*w2.y; acc.z += g4.z*w2.z; acc.w += g4.z*w2.w;
                acc.x += g4.w*w3.x; acc.y += g4.w*w3.y; acc.z += g4.w*w3.z; acc.w += g4.w*w3.w;
            }
            float4 b = *(const float4*)&b2[4 * tc];
            int i = i0 + r;
            float dd = dis[i];
            bf4 o;
            o.a = __float2bfloat16(dd * (acc.x + b.x));
            o.b = __float2bfloat16(dd * (acc.y + b.y));
            o.c = __float2bfloat16(dd * (acc.z + b.z));
            o.d = __float2bfloat16(dd * (acc.w + b.w));
            *(bf4*)(M2ph + (size_t)i * F_OUT + 4 * tc) = o;
        }
    }
    gridbar(bar);
    // ---- P3: weighted pool; block = (g, 512-row chunk), 2 subs x 256 rows -
    {
        int g = blockIdx.x >> 4, q = blockIdx.x & 15;
        int c = t & 127, sub = t >> 7;
        int j0 = q * 512 + sub * 256;
        const unsigned short* Mu = (const unsigned short*)M2ph;
        sm.p3.us[sub][c]       = u[(size_t)(j0 + c) * N_GRAPHS + g];
        sm.p3.us[sub][c + 128] = u[(size_t)(j0 + c + 128) * N_GRAPHS + g];
        __syncthreads();
        float a0 = 0.f, a1 = 0.f, a2 = 0.f, a3 = 0.f, a4 = 0.f, a5 = 0.f, a6 = 0.f, a7 = 0.f;
        for (int jj = 0; jj < 256; jj += 8) {
#define TERM(Q, ACC) ACC += sm.p3.us[sub][jj + Q] * \
            __uint_as_float((unsigned)Mu[(size_t)(j0 + jj + Q) * F_OUT + c] << 16);
            TERM(0, a0) TERM(1, a1) TERM(2, a2) TERM(3, a3)
            TERM(4, a4) TERM(5, a5) TERM(6, a6) TERM(7, a7)
#undef TERM
        }
        float s = ((a0 + a1) + (a2 + a3)) + ((a4 + a5) + (a6 + a7));
        int lo = 0, hi = N_NODES;
        while (lo < hi) { int m = (lo + hi) >> 1; if (batch[m] < g) lo = m + 1; else hi = m; }
        int start = lo;
        hi = N_NODES;
        while (lo < hi) { int m = (lo + hi) >> 1; if (batch[m] < g + 1) lo = m + 1; else hi = m; }
        int cnt = lo - start;
        atomicAdd(&out[(size_t)g * F_OUT + c], s / (float)(cnt > 0 ? cnt : 1));
    }
}

// ---------------------------------------------------------------------------
extern "C" void kernel_launch(void* const* d_in, const int* in_sizes, int n_in,
                              void* d_out, int out_size, void* d_ws, size_t ws_size,
                              hipStream_t stream) {
    const float* X  = (const float*)d_in[0];
    const float* W1 = (const float*)d_in[1];
    const float* b1 = (const float*)d_in[2];
    const float* W2 = (const float*)d_in[3];
    const float* b2 = (const float*)d_in[4];
    const int* ei    = (const int*)d_in[5];
    const int* batch = (const int*)d_in[6];
    float* out = (float*)d_out;

    char* ws = (char*)d_ws;
    // [0,8MB): mask; [2MB,4MB) reused for M2ph (written in P2, after P1's
    // last mask read, barrier-ordered). u/G/Xh do not alias mask.
    unsigned int* mask   = (unsigned int*)(ws);
    __hip_bfloat16* M2ph = (__hip_bfloat16*)(ws + 2097152); // 2 MB
    float* G   = (float*)(ws + 8388608);                    // 4 MB
    __hip_bfloat16* Xh = (__hip_bfloat16*)(ws + 12582912);  // 2 MB
    float* u   = (float*)(ws + 14680064);                   // 2 MB (8192x64)
    float* dis = (float*)(ws + 30441472);                   // 32 KB
    float* sv  = (float*)(ws + 30474240);                   // 32 KB
    int*   bar = (int*)(ws + 33554432);                     // 8 B barrier state

    init_bar<<<1, 256, 0, stream>>>(bar, out);
    mega<<<NB, 256, 0, stream>>>(X, W1, b1, W2, b2, ei, batch,
                                 Xh, mask, dis, sv, G, M2ph, u, out, bar);
}

// Round 15
// 177.706 us; speedup vs baseline: 6.6614x; 6.3884x over previous
//
#include <hip/hip_runtime.h>
#include <hip/hip_bf16.h>

#define N_NODES 8192
#define N_EDGES 262144
#define F_INDIM 128
#define HID 256
#define F_OUT 128
#define N_GRAPHS 64
#define WPR 256              // words per bitmask row
#define CAP 160              // max supported degree
#define NQ 32                // wpool j-chunks

struct alignas(8) bf4 { __hip_bfloat16 a, b, c, d; };

__device__ inline float2 bf2unpack(unsigned int u) {
    float2 r;
    r.x = __uint_as_float(u << 16);          // low ushort  -> col 2l
    r.y = __uint_as_float(u & 0xffff0000u);  // high ushort -> col 2l+1
    return r;
}

// ---------------------------------------------------------------------------
// 1. cast X -> bf16 (blocks 0..1023), zero mask (1024..3071), zero deg (3072..3079)
// ---------------------------------------------------------------------------
__global__ __launch_bounds__(256) void cast_zero(const float* __restrict__ X,
                                                 __hip_bfloat16* __restrict__ Xh,
                                                 unsigned int* __restrict__ mask,
                                                 int* __restrict__ deg) {
    int b = blockIdx.x, t = threadIdx.x;
    if (b < 1024) {                       // 1024*256 = N*F/4 float4 casts
        int i = b * 256 + t;
        float4 v = ((const float4*)X)[i];
        bf4 o;
        o.a = __float2bfloat16(v.x); o.b = __float2bfloat16(v.y);
        o.c = __float2bfloat16(v.z); o.d = __float2bfloat16(v.w);
        ((bf4*)Xh)[i] = o;
    } else if (b < 3072) {                // 2048*256 = 8MB/16B uint4 zeros
        int i = (b - 1024) * 256 + t;
        uint4 z = {0u, 0u, 0u, 0u};
        ((uint4*)mask)[i] = z;
    } else {                              // 8*256 = 2048 uint4 = 8192 ints
        int i = (b - 3072) * 256 + t;
        uint4 z = {0u, 0u, 0u, 0u};
        ((uint4*)deg)[i] = z;
    }
}

// ---------------------------------------------------------------------------
// 2. Edge scatter with exact dedup'd degree: atomicOr returns the old word;
//    the FIRST setter of a bit increments deg. [R2-proven atomics + new count]
// ---------------------------------------------------------------------------
__global__ __launch_bounds__(256) void scatter_edges(const int* __restrict__ ei,
                                                     unsigned int* __restrict__ mask,
                                                     int* __restrict__ deg) {
    int e2 = blockIdx.x * 256 + threadIdx.x;   // covers edges 2*e2, 2*e2+1
    int2 s2 = ((const int2*)ei)[e2];
    int2 d2 = ((const int2*)(ei + N_EDGES))[e2];
#define SCAT(S, D)                                                            \
    if ((unsigned)(S) < N_NODES && (unsigned)(D) < N_NODES) {                 \
        unsigned bd = 1u << ((D) & 31);                                       \
        unsigned o1 = atomicOr(&mask[(size_t)(S) * WPR + ((D) >> 5)], bd);    \
        if (!(o1 & bd)) atomicAdd(&deg[S], 1);                                \
        unsigned bs = 1u << ((S) & 31);                                       \
        unsigned o2 = atomicOr(&mask[(size_t)(D) * WPR + ((S) >> 5)], bs);    \
        if (!(o2 & bs)) atomicAdd(&deg[D], 1);                                \
    }
    SCAT(s2.x, d2.x)
    SCAT(s2.y, d2.y)
#undef SCAT
}

// ---------------------------------------------------------------------------
// 3. spmm_scan: wave per row i. Scans the mask row to an LDS neighbor list;
//    di from own popcount, neighbor dj = rsqrt(deg[j]+1) on the fly
//    (bit-identical to the old dis-table path). Writes G, sv, dis, u.
// ---------------------------------------------------------------------------
__global__ __launch_bounds__(256) void spmm_scan(const unsigned int* __restrict__ mask,
                                                 const __hip_bfloat16* __restrict__ Xh,
                                                 const int* __restrict__ deg,
                                                 const int* __restrict__ batch,
                                                 float* __restrict__ G,
                                                 float* __restrict__ sv,
                                                 float* __restrict__ dis,
                                                 float* __restrict__ u) {
    int w = threadIdx.x >> 6, lane = threadIdx.x & 63;
    int i = blockIdx.x * 4 + w;
    __shared__ int nb[4][CAP];
    __shared__ float nbd[4][CAP];
    __shared__ float ul[4][64];
    ul[w][lane] = 0.0f;
    uint4 v = ((const uint4*)(mask + (size_t)i * WPR))[lane];
    int cnt = __popc(v.x) + __popc(v.y) + __popc(v.z) + __popc(v.w);
    int scan = cnt;
    for (int off = 1; off < 64; off <<= 1) {
        int n = __shfl_up(scan, off);
        if (lane >= off) scan += n;
    }
    int tot = __shfl(scan, 63);
    int idx = scan - cnt;              // exclusive prefix = LDS write base
    int wbase = lane << 7;
    unsigned int wd;
    wd = v.x; while (wd) { int b = __ffs(wd) - 1; wd &= wd - 1; if (idx < CAP) nb[w][idx] = wbase + b;      ++idx; }
    wd = v.y; while (wd) { int b = __ffs(wd) - 1; wd &= wd - 1; if (idx < CAP) nb[w][idx] = wbase + 32 + b; ++idx; }
    wd = v.z; while (wd) { int b = __ffs(wd) - 1; wd &= wd - 1; if (idx < CAP) nb[w][idx] = wbase + 64 + b; ++idx; }
    wd = v.w; while (wd) { int b = __ffs(wd) - 1; wd &= wd - 1; if (idx < CAP) nb[w][idx] = wbase + 96 + b; ++idx; }
    int d = tot > CAP ? CAP : tot;
    float di = rsqrtf((float)(tot + 1));   // own dis from own popcount
    __syncthreads();
    const unsigned int* Xu = (const unsigned int*)Xh;  // row stride 64 uints
    float p = 0.0f;
    for (int t = lane; t < d; t += 64) {
        int j = nb[w][t];
        float dj = rsqrtf((float)(deg[j] + 1));   // identical instr to old table fill
        nbd[w][t] = dj;
        p += dj;
        atomicAdd(&ul[w][batch[j] & 63], dj);
    }
    for (int off = 32; off; off >>= 1) p += __shfl_down(p, off);
    if (lane == 0) {
        sv[i] = di * (di + p);
        dis[i] = di;                              // for fused_gemm epilogue
        atomicAdd(&ul[w][batch[i] & 63], di);     // +I diagonal
    }
    __syncthreads();   // nbd + ul complete
    float2 xi = bf2unpack(Xu[(size_t)i * 64 + lane]);
    float2 a0 = {di * xi.x, di * xi.y};
    float2 a1 = {0,0}, a2 = {0,0}, a3 = {0,0}, a4 = {0,0}, a5 = {0,0}, a6 = {0,0}, a7 = {0,0};
    int k = 0;
    for (; k + 8 <= d; k += 8) {
#define GATH(Q, ACC) { int j = nb[w][k+Q]; float dj = nbd[w][k+Q]; \
        float2 f = bf2unpack(Xu[(size_t)j * 64 + lane]); \
        ACC.x += dj * f.x; ACC.y += dj * f.y; }
        GATH(0, a0) GATH(1, a1) GATH(2, a2) GATH(3, a3)
        GATH(4, a4) GATH(5, a5) GATH(6, a6) GATH(7, a7)
    }
    for (; k < d; ++k) GATH(0, a0)
#undef GATH
    float2 s;
    s.x = ((a0.x + a1.x) + (a2.x + a3.x)) + ((a4.x + a5.x) + (a6.x + a7.x));
    s.y = ((a0.y + a1.y) + (a2.y + a3.y)) + ((a4.y + a5.y) + (a6.y + a7.y));
    float2 o = {di * s.x, di * s.y};
    ((float2*)(G + (size_t)i * F_INDIM))[lane] = o;
    u[(size_t)i * N_GRAPHS + lane] = ul[w][lane];  // coalesced 256B per wave
}

// ---------------------------------------------------------------------------
// 4. fused_gemm  [R10 verbatim] + block 0 zeroes `out` for wpool atomics
// ---------------------------------------------------------------------------
__global__ __launch_bounds__(256) void fused_gemm(const float* __restrict__ G,
                                                  const float* __restrict__ W1,
                                                  const float* __restrict__ b1,
                                                  const float* __restrict__ sv,
                                                  const float* __restrict__ W2,
                                                  const float* __restrict__ b2,
                                                  const float* __restrict__ dis,
                                                  __hip_bfloat16* __restrict__ M2ph,
                                                  float* __restrict__ out) {
    int i0 = blockIdx.x * 16;
    int t = threadIdx.x;
    if (blockIdx.x == 0) {   // zero out (64x128 f32 = 2048 float4)
        float4 z = {0,0,0,0};
        for (int v = t; v < N_GRAPHS * F_OUT / 4; v += 256) ((float4*)out)[v] = z;
    }
    __shared__ float xs[16][F_INDIM];   // 8 KB
    __shared__ float hs[16][HID];       // 16 KB
    for (int v = t; v < 16 * F_INDIM / 4; v += 256) {
        int r = v >> 5, c4 = (v & 31) << 2;
        *(float4*)&xs[r][c4] = *(const float4*)&G[(size_t)(i0 + r) * F_INDIM + c4];
    }
    __syncthreads();
    // ---- stage 1: 4 rows x 4 cols per thread over K=128 ----
    {
        int tc = t & 63, tr = t >> 6;
        float4 acc0 = {0,0,0,0}, acc1 = {0,0,0,0}, acc2 = {0,0,0,0}, acc3 = {0,0,0,0};
        const float* wp = W1 + 4 * tc;
        for (int k = 0; k < F_INDIM; k += 4) {
            float4 w0 = *(const float4*)&wp[(size_t)(k + 0) * HID];
            float4 w1 = *(const float4*)&wp[(size_t)(k + 1) * HID];
            float4 w2 = *(const float4*)&wp[(size_t)(k + 2) * HID];
            float4 w3 = *(const float4*)&wp[(size_t)(k + 3) * HID];
#define ROW(R, ACC) { \
            float4 g4 = *(const float4*)&xs[4 * tr + R][k]; \
            ACC.x += g4.x*w0.x; ACC.y += g4.x*w0.y; ACC.z += g4.x*w0.z; ACC.w += g4.x*w0.w; \
            ACC.x += g4.y*w1.x; ACC.y += g4.y*w1.y; ACC.z += g4.y*w1.z; ACC.w += g4.y*w1.w; \
            ACC.x += g4.z*w2.x; ACC.y += g4.z*w2.y; ACC.z += g4.z*w2.z; ACC.w += g4.z*w2.w; \
            ACC.x += g4.w*w3.x; ACC.y += g4.w*w3.y; ACC.z += g4.w*w3.z; ACC.w += g4.w*w3.w; }
            ROW(0, acc0) ROW(1, acc1) ROW(2, acc2) ROW(3, acc3)
#undef ROW
        }
        float4 b = *(const float4*)&b1[4 * tc];
#define EPI(R, ACC) { \
            int r = 4 * tr + R; float s = sv[i0 + r]; float4 res = ACC; \
            hs[r][4 * tc + 0] = fmaxf(res.x + s * b.x, 0.f); \
            hs[r][4 * tc + 1] = fmaxf(res.y + s * b.y, 0.f); \
            hs[r][4 * tc + 2] = fmaxf(res.z + s * b.z, 0.f); \
            hs[r][4 * tc + 3] = fmaxf(res.w + s * b.w, 0.f); }
        EPI(0, acc0) EPI(1, acc1) EPI(2, acc2) EPI(3, acc3)
#undef EPI
    }
    __syncthreads();
    // ---- stage 2: 2 rows x 4 cols per thread over K=256 ----
    {
        int tc = t & 31, tr = t >> 5;
        float4 acc0 = {0,0,0,0}, acc1 = {0,0,0,0};
        const float* wp = W2 + 4 * tc;
        for (int k = 0; k < HID; k += 4) {
            float4 w0 = *(const float4*)&wp[(size_t)(k + 0) * F_OUT];
            float4 w1 = *(const float4*)&wp[(size_t)(k + 1) * F_OUT];
            float4 w2 = *(const float4*)&wp[(size_t)(k + 2) * F_OUT];
            float4 w3 = *(const float4*)&wp[(size_t)(k + 3) * F_OUT];
#define ROW(R, ACC) { \
            float4 g4 = *(const float4*)&hs[2 * tr + R][k]; \
            ACC.x += g4.x*w0.x; ACC.y += g4.x*w0.y; ACC.z += g4.x*w0.z; ACC.w += g4.x*w0.w; \
            ACC.x += g4.y*w1.x; ACC.y += g4.y*w1.y; ACC.z += g4.y*w1.z; ACC.w += g4.y*w1.w; \
            ACC.x += g4.z*w2.x; ACC.y += g4.z*w2.y; ACC.z += g4.z*w2.z; ACC.w += g4.z*w2.w; \
            ACC.x += g4.w*w3.x; ACC.y += g4.w*w3.y; ACC.z += g4.w*w3.z; ACC.w += g4.w*w3.w; }
            ROW(0, acc0) ROW(1, acc1)
#undef ROW
        }
        float4 b = *(const float4*)&b2[4 * tc];
#define EPI(R, ACC) { \
            int i = i0 + 2 * tr + R; float dd = dis[i]; float4 res = ACC; \
            bf4 o; o.a = __float2bfloat16(dd * (res.x + b.x)); o.b = __float2bfloat16(dd * (res.y + b.y)); \
            o.c = __float2bfloat16(dd * (res.z + b.z)); o.d = __float2bfloat16(dd * (res.w + b.w)); \
            *(bf4*)(M2ph + (size_t)i * F_OUT + 4 * tc) = o; }
        EPI(0, acc0) EPI(1, acc1)
#undef EPI
    }
}

// ---------------------------------------------------------------------------
// 5. wpool: out[g][c] += (1/cnt_g) * sum_{j in chunk q} u[j][g] * M2ph[j][c]
// ---------------------------------------------------------------------------
__global__ __launch_bounds__(128) void wpool(const float* __restrict__ u,
                                             const __hip_bfloat16* __restrict__ M2ph,
                                             const int* __restrict__ batch,
                                             float* __restrict__ out) {
    int g = blockIdx.x, q = blockIdx.y, c = threadIdx.x;
    int j0 = q * (N_NODES / NQ);
    const unsigned short* Mu = (const unsigned short*)M2ph;
    __shared__ float us[N_NODES / NQ];   // 256
    us[c]       = u[(size_t)(j0 + c) * N_GRAPHS + g];
    us[c + 128] = u[(size_t)(j0 + c + 128) * N_GRAPHS + g];
    __syncthreads();
    float a0 = 0.f, a1 = 0.f, a2 = 0.f, a3 = 0.f, a4 = 0.f, a5 = 0.f, a6 = 0.f, a7 = 0.f;
    for (int jj = 0; jj < N_NODES / NQ; jj += 8) {
#define TERM(Q, ACC) ACC += us[jj + Q] * __uint_as_float((unsigned)Mu[(size_t)(j0 + jj + Q) * F_OUT + c] << 16);
        TERM(0, a0) TERM(1, a1) TERM(2, a2) TERM(3, a3)
        TERM(4, a4) TERM(5, a5) TERM(6, a6) TERM(7, a7)
#undef TERM
    }
    float s = ((a0 + a1) + (a2 + a3)) + ((a4 + a5) + (a6 + a7));
    // cnt_g via binary search on sorted batch
    int lo = 0, hi = N_NODES;
    while (lo < hi) { int m = (lo + hi) >> 1; if (batch[m] < g) lo = m + 1; else hi = m; }
    int start = lo;
    hi = N_NODES;
    while (lo < hi) { int m = (lo + hi) >> 1; if (batch[m] < g + 1) lo = m + 1; else hi = m; }
    int cnt = lo - start;
    atomicAdd(&out[(size_t)g * F_OUT + c], s / (float)(cnt > 0 ? cnt : 1));
}

// ---------------------------------------------------------------------------
extern "C" void kernel_launch(void* const* d_in, const int* in_sizes, int n_in,
                              void* d_out, int out_size, void* d_ws, size_t ws_size,
                              hipStream_t stream) {
    const float* X  = (const float*)d_in[0];
    const float* W1 = (const float*)d_in[1];
    const float* b1 = (const float*)d_in[2];
    const float* W2 = (const float*)d_in[3];
    const float* b2 = (const float*)d_in[4];
    const int* ei    = (const int*)d_in[5];
    const int* batch = (const int*)d_in[6];
    float* out = (float*)d_out;

    char* ws = (char*)d_ws;
    // [0, 8MB): mask during build. After spmm_scan (last mask reader), the
    // [2MB,4MB) slice is reused for M2ph (written by fused_gemm, stream-
    // ordered after spmm_scan). u/G/Xh/deg/dis/sv do not alias mask.
    unsigned int* mask   = (unsigned int*)(ws);
    __hip_bfloat16* M2ph = (__hip_bfloat16*)(ws + 2097152); // 2 MB (8192x128)
    float* G   = (float*)(ws + 8388608);                    // 4 MB (8192x128 f32)
    __hip_bfloat16* Xh = (__hip_bfloat16*)(ws + 12582912);  // 2 MB (8192x128 bf16)
    float* u   = (float*)(ws + 14680064);                   // 2 MB (8192x64)
    int*   deg = (int*)(ws + 30408704);                     // 32 KB
    float* dis = (float*)(ws + 30441472);                   // 32 KB
    float* sv  = (float*)(ws + 30474240);                   // 32 KB

    cast_zero<<<3080, 256, 0, stream>>>(X, Xh, mask, deg);
    scatter_edges<<<N_EDGES / 512, 256, 0, stream>>>(ei, mask, deg);
    spmm_scan<<<N_NODES / 4, 256, 0, stream>>>(mask, Xh, deg, batch, G, sv, dis, u);
    fused_gemm<<<N_NODES / 16, 256, 0, stream>>>(G, W1, b1, sv, W2, b2, dis, M2ph, out);
    wpool<<<dim3(N_GRAPHS, NQ), 128, 0, stream>>>(u, M2ph, batch, out);
}